// Round 10
// baseline (101.661 us; speedup 1.0000x reference)
//
#include <hip/hip_runtime.h>

// Problem constants (from reference)
#define BQ 2
#define HQ 16
#define SQ 8192
#define DQ 128
#define STR 16
#define NWIN 511     // (8192-32)/16 + 1
#define NBLK 512     // NWIN + 1 zero block
#define WPB 4        // windows per workgroup
#define NWG_PER_HEAD 128  // ceil(511/4)

typedef float f32x4 __attribute__((ext_vector_type(4)));
typedef float f32x16 __attribute__((ext_vector_type(16)));
typedef short s16x8 __attribute__((ext_vector_type(8)));
typedef short s16x4 __attribute__((ext_vector_type(4)));

// LDS 36 KB map (pyramid reuses the dead kin region):
//   kin @0     [80 rows][256B] = 20480   (4 windows, 50% overlap, loaded once)
//   s0  @20480 [64][256] = 16384
//   s1  @0     [32][256] =  8192  (kin dead)
//   s2  @8192  [16][256] =  4096
//   s3  @12288 [8][256]  =  2048
//   s4  @14336 [4][256]  =  1024
#define R_KIN 0u
#define R_S0  20480u
#define R_S1  0u
#define R_S2  8192u
#define R_S3  12288u
#define R_S4  14336u

// XOR swizzle keyed on 512B granule (G4/T2). Involution on global LDS byte
// offsets. Manual-XOR soundness: inner offsets < 256B occupy bits 4-7 only;
// the key ((addr>>9)&7) comes solely from the row field, so
// swz(rowpart + inner) == rowpart + (inner ^ (key<<4)).
static __device__ __forceinline__ unsigned swz(unsigned b) {
    return b ^ (((b >> 9) & 7u) << 4);
}

static __device__ __forceinline__ short f2bf(float f) {
    __bf16 h = (__bf16)f;
    return __builtin_bit_cast(short, h);
}

// cheap silu: v_rcp_f32 instead of the exact-div sequence (~10 instrs)
static __device__ __forceinline__ float silu(float v) {
    return v * __builtin_amdgcn_rcpf(1.f + __expf(-v));
}

// ---- pass 0 (merged prep): weight permute + bias0 + zero-blocks ----
// ws layout (shorts):
//   wd32 s0 @0      [4ct32][16t][512]   (32768)   32x32x16 frag order
//   wd32 s1 @32768  [4ct32][16t][512]   (32768)
//   wd16 s2 @65536  [8ct][8kt][512]     (32768)   16x16x32 frag order
//   wd16 s3 @98304, s4 @131072
//   wstop   @163840 [8ct][4kt][512]     (16384)
//   bias0 f32[16][128] at byte 360448
__global__ void prep_kernel(const float* __restrict__ wd,
                            const float* __restrict__ wstop,
                            const float* __restrict__ pe,
                            short* __restrict__ o,
                            float* __restrict__ bias,
                            float* __restrict__ out) {
    int blk = blockIdx.x;
    if (blk < 704) {
        int i = blk * 256 + threadIdx.x;
        if (i < 65536) {
            // 32-wide frag order for stages 0,1:
            // o[s*32768 + ct*8192 + t*512 + ln*8 + e] =
            //   W_s[ct*32+(ln&31)][t*16+(ln>>5)*8+e]
            int s   = i >> 15;
            int r   = i & 32767;
            int ct  = r >> 13;
            int r2  = r & 8191;
            int t   = r2 >> 9;
            int r3  = r2 & 511;
            int ln  = r3 >> 3;
            int e   = r3 & 7;
            int ch  = ct * 32 + (ln & 31);
            int k   = t * 16 + (ln >> 5) * 8 + e;
            o[i] = f2bf(wd[((size_t)(s * 128 + ch)) * 256 + k]);
        } else if (i < 163840) {
            // 16-wide frag order for stages 2,3,4
            int j   = i - 65536;
            int s   = j >> 15;           // 0..2 -> stage 2..4
            int r   = j & 32767;
            int ct  = r >> 12;
            int r2  = r & 4095;
            int kt  = r2 >> 9;
            int r3  = r2 & 511;
            int ln  = r3 >> 3;
            int e   = r3 & 7;
            int ch  = ct * 16 + (ln & 15);
            int k   = kt * 32 + (ln >> 4) * 8 + e;
            o[i] = f2bf(wd[((size_t)((s + 2) * 128 + ch)) * 256 + k]);
        } else if (i < 180224) {
            int j   = i - 163840;
            int ct  = j >> 11;
            int r2  = j & 2047;
            int kt  = r2 >> 9;
            int r3  = r2 & 511;
            int ln  = r3 >> 3;
            int e   = r3 & 7;
            int ch  = ct * 16 + (ln & 15);
            int k   = kt * 32 + (ln >> 4) * 8 + e;
            o[i] = f2bf(wstop[ch * 128 + k]);
        }
    } else if (blk < 712) {
        int oo = (blk - 704) * 256 + threadIdx.x;   // 0..2047
        int j = oo >> 7;
        int c = oo & 127;
        const float* w  = wd + (size_t)c * 256;
        const float* p0 = pe + (2 * j) * DQ;
        const float* p1 = pe + (2 * j + 1) * DQ;
        float s = 0.f;
        #pragma unroll 4
        for (int i = 0; i < 128; ++i) s += w[i] * p0[i];
        #pragma unroll 4
        for (int i = 0; i < 128; ++i) s += w[i + 128] * p1[i];
        bias[oo] = s;
    } else {
        int i = (blk - 712) * 256 + threadIdx.x;  // 4096 = 32 heads * 128
        int bh = i >> 7, d = i & 127;
        out[(size_t)bh * NBLK * DQ + d] = 0.f;
    }
}

// ---- pass 1: fused compressor ----
// Stages 0,1: 32x32x16 MFMA (wave = 32-ch tile x row-group) -> halves LDS
// read amplification on the two biggest stages. Stages 2-4 + stop: 16x16x32.
// 36KB LDS, VGPR<=64 -> 4 blocks/CU = 32 waves/CU, spill-free.
__global__ __launch_bounds__(512, 8)
void fused_kernel(const float* __restrict__ kin,
                  const short* __restrict__ wdb,
                  const float* __restrict__ bias0,
                  float* __restrict__ out) {
    __shared__ __align__(16) unsigned char lds[36864];

    const int bh = blockIdx.x >> 7;            // 0..31
    const int w0 = (blockIdx.x & 127) * WPB;   // first window of this group
    const int tid  = threadIdx.x;
    const int lane = tid & 63;
    const int wave = tid >> 6;
    const int kl   = lane >> 4;                // 16x16 stages
    const int nl   = lane & 15;
    const int lo5  = lane & 31;                // 32x32 stages
    const int hi   = lane >> 5;
    const int ct32 = wave & 3;                 // 32-ch tile 0..3
    const int rg   = wave >> 2;                // row-group 0..1
    const int ct   = wave;                     // 16-ch tile 0..7

    const float* kb = kin + (size_t)bh * SQ * DQ;

    // ---- phase A: 80 rows x 16 chunks = 1280 tasks, loaded once ----
    #pragma unroll
    for (int it = 0; it < 3; ++it) {
        int task = tid + it * 512;
        if (task < 1280) {
            int rr = task >> 4;               // 0..79
            int c8 = task & 15;
            int srow = STR * w0 + rr;
            if (srow > SQ - 1) srow = SQ - 1; // clamp (feeds invalid window only)
            const float* kp = kb + (size_t)srow * DQ + c8 * 8;
            f32x4 a0 = *(const f32x4*)kp;
            f32x4 a1 = *(const f32x4*)(kp + 4);
            s16x8 v;
            v[0] = f2bf(a0[0]); v[1] = f2bf(a0[1]); v[2] = f2bf(a0[2]); v[3] = f2bf(a0[3]);
            v[4] = f2bf(a1[0]); v[5] = f2bf(a1[1]); v[6] = f2bf(a1[2]); v[7] = f2bf(a1[3]);
            *(s16x8*)(lds + swz(R_KIN + (unsigned)((rr << 8) + (c8 << 4)))) = v;
        }
    }

    const unsigned kxr = ((unsigned)(lo5 & 7)) << 4;        // read-side key
    const unsigned kxw = ((unsigned)((lo5 >> 1) & 7)) << 4; // write-side key
    const unsigned h4  = ((unsigned)hi << 4) ^ kxr;
    __syncthreads();   // kin ready

    // ---- stage 0 (32x32x16): rows rg*32+lo5, channels ct32*32.., K=256 ----
    {
        // kin row (even) for out-row d=rg*32+lo5: 16*(d>>4) + 2*(d&15)
        const unsigned rowb = R_KIN +
            ((unsigned)(32 * rg + 16 * (lo5 >> 4) + 2 * (lo5 & 15)) << 8);
        f32x16 acc;
        #pragma unroll
        for (int a = 0; a < 4; ++a) {
            f32x4 b4 = *(const f32x4*)(bias0 + (lo5 & 15) * 128 + ct32 * 32 + a * 8 + hi * 4);
            acc[4 * a + 0] = b4[0]; acc[4 * a + 1] = b4[1];
            acc[4 * a + 2] = b4[2]; acc[4 * a + 3] = b4[3];
        }
        #pragma unroll
        for (int chunk = 0; chunk < 4; ++chunk) {
            s16x8 wf[4];
            #pragma unroll
            for (int q = 0; q < 4; ++q)
                wf[q] = *(const s16x8*)(wdb + ct32 * 8192 + (chunk * 4 + q) * 512 + lane * 8);
            #pragma unroll
            for (int q = 0; q < 4; ++q) {
                const int t = chunk * 4 + q;
                unsigned addr = rowb + ((t >= 8) ? 256u : 0u)
                              + (((unsigned)((t & 7) << 5)) ^ h4);
                s16x8 bb = *(const s16x8*)(lds + addr);
                acc = __builtin_amdgcn_mfma_f32_32x32x16_bf16(wf[q], bb, acc, 0, 0, 0);
            }
        }
        const unsigned d = (unsigned)(rg * 32 + lo5);
        #pragma unroll
        for (int a = 0; a < 4; ++a) {
            s16x4 v;
            v[0] = f2bf(silu(acc[4 * a + 0])); v[1] = f2bf(silu(acc[4 * a + 1]));
            v[2] = f2bf(silu(acc[4 * a + 2])); v[3] = f2bf(silu(acc[4 * a + 3]));
            unsigned ob = R_S0 + (d << 8)
                        + (((unsigned)(ct32 * 64 + a * 16 + hi * 8)) ^ kxw);
            *(s16x4*)(lds + ob) = v;
        }
    }
    __syncthreads();

    // ---- stage 1 (32x32x16): 64 in rows -> 32 out rows; rg==0 waves only ----
    if (rg == 0) {
        const unsigned rowb = R_S0 + ((unsigned)(2 * lo5) << 8);
        f32x16 acc = {};
        #pragma unroll
        for (int chunk = 0; chunk < 4; ++chunk) {
            s16x8 wf[4];
            #pragma unroll
            for (int q = 0; q < 4; ++q)
                wf[q] = *(const s16x8*)(wdb + 32768 + ct32 * 8192 + (chunk * 4 + q) * 512 + lane * 8);
            #pragma unroll
            for (int q = 0; q < 4; ++q) {
                const int t = chunk * 4 + q;
                unsigned addr = rowb + ((t >= 8) ? 256u : 0u)
                              + (((unsigned)((t & 7) << 5)) ^ h4);
                s16x8 bb = *(const s16x8*)(lds + addr);
                acc = __builtin_amdgcn_mfma_f32_32x32x16_bf16(wf[q], bb, acc, 0, 0, 0);
            }
        }
        const unsigned d = (unsigned)lo5;
        #pragma unroll
        for (int a = 0; a < 4; ++a) {
            s16x4 v;
            v[0] = f2bf(silu(acc[4 * a + 0])); v[1] = f2bf(silu(acc[4 * a + 1]));
            v[2] = f2bf(silu(acc[4 * a + 2])); v[3] = f2bf(silu(acc[4 * a + 3]));
            unsigned ob = R_S1 + (d << 8)
                        + (((unsigned)(ct32 * 64 + a * 16 + hi * 8)) ^ kxw);
            *(s16x4*)(lds + ob) = v;
        }
    }
    __syncthreads();

    // 4 b128 reads (P/Q bases + immediates) + 4 MFMAs into accv (16x16x32)
#define K_HALF_AT(P, Q, off, accv) {                                           \
        s16x8 aa0 = *(const s16x8*)((P) + (off));                              \
        s16x8 aa1 = *(const s16x8*)((Q) + (off));                              \
        s16x8 aa2 = *(const s16x8*)((P) + (off) + 128);                        \
        s16x8 aa3 = *(const s16x8*)((Q) + (off) + 128);                        \
        accv = __builtin_amdgcn_mfma_f32_16x16x32_bf16(wfh[0], aa0, accv, 0, 0, 0); \
        accv = __builtin_amdgcn_mfma_f32_16x16x32_bf16(wfh[1], aa1, accv, 0, 0, 0); \
        accv = __builtin_amdgcn_mfma_f32_16x16x32_bf16(wfh[2], aa2, accv, 0, 0, 0); \
        accv = __builtin_amdgcn_mfma_f32_16x16x32_bf16(wfh[3], aa3, accv, 0, 0, 0); }

    // ---- stages 2..4 (16x16x32): 1 n-tile each, valid rows 16,8,4 ----
    const unsigned rin[3]  = {R_S1, R_S2, R_S3};
    const unsigned rout[3] = {R_S2, R_S3, R_S4};
    const short* wb16 = wdb + 65536 + ct * 4096 + lane * 8;
    #pragma unroll
    for (int s = 2; s <= 4; ++s) {
        const int outRows = 32 >> (s - 1);       // 16,8,4
        int d = nl;
        int dc = (d < outRows) ? d : outRows - 1;
        f32x4 acc0 = {0.f, 0.f, 0.f, 0.f};
        #pragma unroll
        for (int half = 0; half < 2; ++half) {
            s16x8 wfh[4];
            #pragma unroll
            for (int kt = 0; kt < 4; ++kt)
                wfh[kt] = *(const s16x8*)(wb16 + (s - 2) * 32768 + (half * 4 + kt) * 512);
            unsigned pb = swz(rin[s - 2] + ((unsigned)(2 * dc + half) << 8) + (unsigned)(kl << 4));
            const unsigned char* P = lds + pb;
            const unsigned char* Q = lds + (pb ^ 64u);
            K_HALF_AT(P, Q, 0, acc0);
        }
        if (d < outRows) {
            s16x4 v;
            v[0] = f2bf(silu(acc0[0])); v[1] = f2bf(silu(acc0[1]));
            v[2] = f2bf(silu(acc0[2])); v[3] = f2bf(silu(acc0[3]));
            *(s16x4*)(lds + swz(rout[s - 2] + ((unsigned)d << 8) + (unsigned)(ct * 32 + kl * 8))) = v;
        }
        __syncthreads();
    }

    // ---- w_stop: input R_S4 [4][256B], K=128, no activation -> global f32 ----
    {
        s16x8 wfh[4];
        #pragma unroll
        for (int kt = 0; kt < 4; ++kt)
            wfh[kt] = *(const s16x8*)(wdb + 163840 + ct * 2048 + kt * 512 + lane * 8);
        int d = nl;
        int dc = (d < WPB) ? d : WPB - 1;
        f32x4 acc = {0.f, 0.f, 0.f, 0.f};
        unsigned pb = swz(R_S4 + ((unsigned)dc << 8) + (unsigned)(kl << 4));
        const unsigned char* P = lds + pb;
        const unsigned char* Q = lds + (pb ^ 64u);
        K_HALF_AT(P, Q, 0, acc);
        int w = w0 + d;
        if (d < WPB && w < NWIN) {
            // lane holds channels ct*16+kl*4 .. +3 of window w: one dwordx4
            *(f32x4*)(out + ((size_t)bh * NBLK + (w + 1)) * DQ + ct * 16 + kl * 4) = acc;
        }
    }
#undef K_HALF_AT
}

extern "C" void kernel_launch(void* const* d_in, const int* in_sizes, int n_in,
                              void* d_out, int out_size, void* d_ws, size_t ws_size,
                              hipStream_t stream) {
    const float* kin   = (const float*)d_in[0];
    const float* pe    = (const float*)d_in[1];
    const float* wdown = (const float*)d_in[2];
    const float* wstop = (const float*)d_in[3];
    float* out = (float*)d_out;
    short* wbf  = (short*)d_ws;                       // 180224 shorts (frag-order)
    float* bias = (float*)((char*)d_ws + 360448);     // f32[2048]

    prep_kernel<<<728, 256, 0, stream>>>(wdown, wstop, pe, wbf, bias, out);
    fused_kernel<<<BQ * HQ * NWG_PER_HEAD, 512, 0, stream>>>(kin, wbf, bias, out);
}

// Round 12
// 101.493 us; speedup vs baseline: 1.0017x; 1.0017x over previous
//
#include <hip/hip_runtime.h>

// Problem constants (from reference)
#define BQ 2
#define HQ 16
#define SQ 8192
#define DQ 128
#define STR 16
#define NWIN 511     // (8192-32)/16 + 1
#define NBLK 512     // NWIN + 1 zero block
#define WPB 4        // windows per workgroup
#define NWG_PER_HEAD 128  // ceil(511/4)

typedef float f32x4 __attribute__((ext_vector_type(4)));
typedef short s16x8 __attribute__((ext_vector_type(8)));
typedef short s16x4 __attribute__((ext_vector_type(4)));

// LDS 36 KB map (pyramid reuses the dead kin region):
//   kin @0     [80 rows][256B] = 20480   (4 windows, 50% overlap, loaded once)
//   s0  @20480 [64][256] = 16384
//   s1  @0     [32][256] =  8192  (kin dead)
//   s2  @8192  [16][256] =  4096
//   s3  @12288 [8][256]  =  2048
//   s4  @14336 [4][256]  =  1024
#define R_KIN 0u
#define R_S0  20480u
#define R_S1  0u
#define R_S2  8192u
#define R_S3  12288u
#define R_S4  14336u

// XOR swizzle keyed on 512B granule (G4/T2). Involution on global LDS byte
// offsets. HOIST SOUNDNESS: stage-0 B rows are 32rg+2nl (+1 odd half,
// +16 rows per n-tile) -> key (row>>1)&7 = nl&7 invariant over rg/n/half;
// stage-1 rows 32rg+2nl likewise. kt/n deltas are pure immediates; bit-6
// collisions handled by the P/Q = P^64 pair. (R11 bug: stage-0 used the
// stage-1 2d-mapping 64rg/+8192 and read past the 80-row kin region.)
static __device__ __forceinline__ unsigned swz(unsigned b) {
    return b ^ (((b >> 9) & 7u) << 4);
}

static __device__ __forceinline__ short f2bf(float f) {
    __bf16 h = (__bf16)f;
    return __builtin_bit_cast(short, h);
}

// cheap silu: v_rcp_f32 instead of the exact-div sequence (~10 instrs)
static __device__ __forceinline__ float silu(float v) {
    return v * __builtin_amdgcn_rcpf(1.f + __expf(-v));
}

// ---- pass 0 (merged prep): weight permute + bias0 + zero-blocks ----
// ws: wd_bf frag-order [5 stages][8ct][8kt][512] (163840 sh) + wstop
// frag-order (16384 sh) + bias0 f32[16][128] at byte 360448.
__global__ void prep_kernel(const float* __restrict__ wd,
                            const float* __restrict__ wstop,
                            const float* __restrict__ pe,
                            short* __restrict__ o,
                            float* __restrict__ bias,
                            float* __restrict__ out) {
    int blk = blockIdx.x;
    if (blk < 704) {
        int i = blk * 256 + threadIdx.x;
        if (i < 163840) {
            int s   = i >> 15;
            int r   = i & 32767;
            int ct  = r >> 12;
            int r2  = r & 4095;
            int kt  = r2 >> 9;
            int r3  = r2 & 511;
            int ln  = r3 >> 3;
            int e   = r3 & 7;
            int ch  = ct * 16 + (ln & 15);
            int k   = kt * 32 + (ln >> 4) * 8 + e;
            o[i] = f2bf(wd[((size_t)(s * 128 + ch)) * 256 + k]);
        } else if (i < 180224) {
            int j   = i - 163840;
            int ct  = j >> 11;
            int r2  = j & 2047;
            int kt  = r2 >> 9;
            int r3  = r2 & 511;
            int ln  = r3 >> 3;
            int e   = r3 & 7;
            int ch  = ct * 16 + (ln & 15);
            int k   = kt * 32 + (ln >> 4) * 8 + e;
            o[i] = f2bf(wstop[ch * 128 + k]);
        }
    } else if (blk < 712) {
        int oo = (blk - 704) * 256 + threadIdx.x;   // 0..2047
        int j = oo >> 7;
        int c = oo & 127;
        const float* w  = wd + (size_t)c * 256;
        const float* p0 = pe + (2 * j) * DQ;
        const float* p1 = pe + (2 * j + 1) * DQ;
        float s = 0.f;
        #pragma unroll 4
        for (int i = 0; i < 128; ++i) s += w[i] * p0[i];
        #pragma unroll 4
        for (int i = 0; i < 128; ++i) s += w[i + 128] * p1[i];
        bias[oo] = s;
    } else {
        int i = (blk - 712) * 256 + threadIdx.x;  // 4096 = 32 heads * 128
        int bh = i >> 7, d = i & 127;
        out[(size_t)bh * NBLK * DQ + d] = 0.f;
    }
}

// ---- pass 1: fused compressor ----
// s0/s1: 2-D wave tiles (32 rows x 32 ch, 4 independent 16x16x32 acc chains)
// -> each B-fragment feeds 2 MFMAs, halving s0/s1 LDS reads vs R9 while
// keeping R9's ILP and all-wave occupancy. Tail (s2-s4, stop) = R9 verbatim.
// 36KB LDS, VGPR<=64 -> 4 blocks/CU = 32 waves/CU, spill-free.
__global__ __launch_bounds__(512, 8)
void fused_kernel(const float* __restrict__ kin,
                  const short* __restrict__ wdb,
                  const float* __restrict__ bias0,
                  float* __restrict__ out) {
    __shared__ __align__(16) unsigned char lds[36864];

    const int bh = blockIdx.x >> 7;            // 0..31
    const int w0 = (blockIdx.x & 127) * WPB;   // first window of this group
    const int tid  = threadIdx.x;
    const int lane = tid & 63;
    const int wave = tid >> 6;
    const int kl   = lane >> 4;                // 0..3
    const int nl   = lane & 15;                // 0..15
    const int rg   = wave >> 2;                // row-group 0..1 (s0/s1)
    const int cg   = wave & 3;                 // ch-group 0..3 (s0/s1)
    const int ct   = wave;                     // 16-ch tile (tail stages)

    const float* kb = kin + (size_t)bh * SQ * DQ;

    // ---- phase A: 80 rows x 16 chunks = 1280 tasks, loaded once ----
    #pragma unroll
    for (int it = 0; it < 3; ++it) {
        int task = tid + it * 512;
        if (task < 1280) {
            int rr = task >> 4;               // 0..79
            int c8 = task & 15;
            int srow = STR * w0 + rr;
            if (srow > SQ - 1) srow = SQ - 1; // clamp (feeds invalid window only)
            const float* kp = kb + (size_t)srow * DQ + c8 * 8;
            f32x4 a0 = *(const f32x4*)kp;
            f32x4 a1 = *(const f32x4*)(kp + 4);
            s16x8 v;
            v[0] = f2bf(a0[0]); v[1] = f2bf(a0[1]); v[2] = f2bf(a0[2]); v[3] = f2bf(a0[3]);
            v[4] = f2bf(a1[0]); v[5] = f2bf(a1[1]); v[6] = f2bf(a1[2]); v[7] = f2bf(a1[3]);
            *(s16x8*)(lds + swz(R_KIN + (unsigned)((rr << 8) + (c8 << 4)))) = v;
        }
    }
    __syncthreads();   // kin ready

    const int ct0 = 2 * cg, ct1 = 2 * cg + 1;
    const short* wA = wdb + ct0 * 4096 + lane * 8;   // ct0 frag base
    const short* wB = wdb + ct1 * 4096 + lane * 8;   // ct1 frag base

    // ---- stage 0: wave tile = n-tiles {2rg, 2rg+1} x ch 32cg..+31, K=256.
    //      Window mapping: out-row d=16n+nl <- kin rows 16n+2nl (+1).
    //      Base row 32rg+2nl; second n-tile delta = +16 rows = +4096 B. ----
    {
        f32x4 acc00 = {}, acc10 = {};   // n=2rg,   ct0 / ct1
        f32x4 acc01 = {}, acc11 = {};   // n=2rg+1, ct0 / ct1
        unsigned pb = swz(R_KIN + ((unsigned)(32 * rg + 2 * nl) << 8) + (unsigned)(kl << 4));
        const unsigned char* P = lds + pb;
        const unsigned char* Q = lds + (pb ^ 64u);
        #pragma unroll
        for (int c = 0; c < 4; ++c) {
            const int off = ((c & 1) << 7) + ((c >> 1) << 8);  // 0,128,256,384
            s16x8 wf00 = *(const s16x8*)(wA + (2 * c) * 512);
            s16x8 wf01 = *(const s16x8*)(wA + (2 * c + 1) * 512);
            s16x8 wf10 = *(const s16x8*)(wB + (2 * c) * 512);
            s16x8 wf11 = *(const s16x8*)(wB + (2 * c + 1) * 512);
            s16x8 b0 = *(const s16x8*)(P + off);
            s16x8 b1 = *(const s16x8*)(Q + off);
            s16x8 b2 = *(const s16x8*)(P + off + 4096);
            s16x8 b3 = *(const s16x8*)(Q + off + 4096);
            acc00 = __builtin_amdgcn_mfma_f32_16x16x32_bf16(wf00, b0, acc00, 0, 0, 0);
            acc10 = __builtin_amdgcn_mfma_f32_16x16x32_bf16(wf10, b0, acc10, 0, 0, 0);
            acc01 = __builtin_amdgcn_mfma_f32_16x16x32_bf16(wf00, b2, acc01, 0, 0, 0);
            acc11 = __builtin_amdgcn_mfma_f32_16x16x32_bf16(wf10, b2, acc11, 0, 0, 0);
            acc00 = __builtin_amdgcn_mfma_f32_16x16x32_bf16(wf01, b1, acc00, 0, 0, 0);
            acc10 = __builtin_amdgcn_mfma_f32_16x16x32_bf16(wf11, b1, acc10, 0, 0, 0);
            acc01 = __builtin_amdgcn_mfma_f32_16x16x32_bf16(wf01, b3, acc01, 0, 0, 0);
            acc11 = __builtin_amdgcn_mfma_f32_16x16x32_bf16(wf11, b3, acc11, 0, 0, 0);
        }
        // epilogue: bias (L1-hot reload) + silu + ds_write_b64 x4
        const f32x4 bv0 = *(const f32x4*)(bias0 + nl * 128 + ct0 * 16 + kl * 4);
        const f32x4 bv1 = *(const f32x4*)(bias0 + nl * 128 + ct1 * 16 + kl * 4);
        #pragma unroll
        for (int n = 0; n < 2; ++n) {
            f32x4 a0 = n ? acc01 : acc00;
            f32x4 a1 = n ? acc11 : acc10;
            unsigned d = (unsigned)(16 * (2 * rg + n) + nl);
            s16x4 v;
            v[0] = f2bf(silu(a0[0] + bv0[0])); v[1] = f2bf(silu(a0[1] + bv0[1]));
            v[2] = f2bf(silu(a0[2] + bv0[2])); v[3] = f2bf(silu(a0[3] + bv0[3]));
            *(s16x4*)(lds + swz(R_S0 + (d << 8) + (unsigned)(ct0 * 32 + kl * 8))) = v;
            v[0] = f2bf(silu(a1[0] + bv1[0])); v[1] = f2bf(silu(a1[1] + bv1[1]));
            v[2] = f2bf(silu(a1[2] + bv1[2])); v[3] = f2bf(silu(a1[3] + bv1[3]));
            *(s16x4*)(lds + swz(R_S0 + (d << 8) + (unsigned)(ct1 * 32 + kl * 8))) = v;
        }
    }
    __syncthreads();

    // ---- stage 1: out 32 rows; wave = rows 16rg..+15 x ch 32cg..+31.
    //      Input rows 2d,2d+1 = 32rg+2nl (+1). ----
    {
        f32x4 acc0 = {}, acc1 = {};
        unsigned pb = swz(R_S0 + ((unsigned)(32 * rg + 2 * nl) << 8) + (unsigned)(kl << 4));
        const unsigned char* P = lds + pb;
        const unsigned char* Q = lds + (pb ^ 64u);
        #pragma unroll
        for (int c = 0; c < 4; ++c) {
            const int off = ((c & 1) << 7) + ((c >> 1) << 8);
            s16x8 wf00 = *(const s16x8*)(wA + 32768 + (2 * c) * 512);
            s16x8 wf01 = *(const s16x8*)(wA + 32768 + (2 * c + 1) * 512);
            s16x8 wf10 = *(const s16x8*)(wB + 32768 + (2 * c) * 512);
            s16x8 wf11 = *(const s16x8*)(wB + 32768 + (2 * c + 1) * 512);
            s16x8 b0 = *(const s16x8*)(P + off);
            s16x8 b1 = *(const s16x8*)(Q + off);
            acc0 = __builtin_amdgcn_mfma_f32_16x16x32_bf16(wf00, b0, acc0, 0, 0, 0);
            acc1 = __builtin_amdgcn_mfma_f32_16x16x32_bf16(wf10, b0, acc1, 0, 0, 0);
            acc0 = __builtin_amdgcn_mfma_f32_16x16x32_bf16(wf01, b1, acc0, 0, 0, 0);
            acc1 = __builtin_amdgcn_mfma_f32_16x16x32_bf16(wf11, b1, acc1, 0, 0, 0);
        }
        unsigned d = (unsigned)(16 * rg + nl);
        s16x4 v;
        v[0] = f2bf(silu(acc0[0])); v[1] = f2bf(silu(acc0[1]));
        v[2] = f2bf(silu(acc0[2])); v[3] = f2bf(silu(acc0[3]));
        *(s16x4*)(lds + swz(R_S1 + (d << 8) + (unsigned)(ct0 * 32 + kl * 8))) = v;
        v[0] = f2bf(silu(acc1[0])); v[1] = f2bf(silu(acc1[1]));
        v[2] = f2bf(silu(acc1[2])); v[3] = f2bf(silu(acc1[3]));
        *(s16x4*)(lds + swz(R_S1 + (d << 8) + (unsigned)(ct1 * 32 + kl * 8))) = v;
    }
    __syncthreads();

    // 4 b128 reads (P/Q bases + immediates) + 4 MFMAs into accv (16x16x32)
#define K_HALF_AT(P, Q, off, accv) {                                           \
        s16x8 aa0 = *(const s16x8*)((P) + (off));                              \
        s16x8 aa1 = *(const s16x8*)((Q) + (off));                              \
        s16x8 aa2 = *(const s16x8*)((P) + (off) + 128);                        \
        s16x8 aa3 = *(const s16x8*)((Q) + (off) + 128);                        \
        accv = __builtin_amdgcn_mfma_f32_16x16x32_bf16(wfh[0], aa0, accv, 0, 0, 0); \
        accv = __builtin_amdgcn_mfma_f32_16x16x32_bf16(wfh[1], aa1, accv, 0, 0, 0); \
        accv = __builtin_amdgcn_mfma_f32_16x16x32_bf16(wfh[2], aa2, accv, 0, 0, 0); \
        accv = __builtin_amdgcn_mfma_f32_16x16x32_bf16(wfh[3], aa3, accv, 0, 0, 0); }

    // ---- stages 2..4 (R9 verbatim): 1 n-tile each, valid rows 16,8,4 ----
    const unsigned rin[3]  = {R_S1, R_S2, R_S3};
    const unsigned rout[3] = {R_S2, R_S3, R_S4};
    const short* wb16 = wdb + ct * 4096 + lane * 8;
    #pragma unroll
    for (int s = 2; s <= 4; ++s) {
        const int outRows = 32 >> (s - 1);       // 16,8,4
        int d = nl;
        int dc = (d < outRows) ? d : outRows - 1;
        f32x4 acc0 = {0.f, 0.f, 0.f, 0.f};
        #pragma unroll
        for (int half = 0; half < 2; ++half) {
            s16x8 wfh[4];
            #pragma unroll
            for (int kt = 0; kt < 4; ++kt)
                wfh[kt] = *(const s16x8*)(wb16 + s * 32768 + (half * 4 + kt) * 512);
            unsigned pb = swz(rin[s - 2] + ((unsigned)(2 * dc + half) << 8) + (unsigned)(kl << 4));
            const unsigned char* P = lds + pb;
            const unsigned char* Q = lds + (pb ^ 64u);
            K_HALF_AT(P, Q, 0, acc0);
        }
        if (d < outRows) {
            s16x4 v;
            v[0] = f2bf(silu(acc0[0])); v[1] = f2bf(silu(acc0[1]));
            v[2] = f2bf(silu(acc0[2])); v[3] = f2bf(silu(acc0[3]));
            *(s16x4*)(lds + swz(rout[s - 2] + ((unsigned)d << 8) + (unsigned)(ct * 32 + kl * 8))) = v;
        }
        __syncthreads();
    }

    // ---- w_stop: input R_S4 [4][256B], K=128, no activation -> global f32 ----
    {
        s16x8 wfh[4];
        #pragma unroll
        for (int kt = 0; kt < 4; ++kt)
            wfh[kt] = *(const s16x8*)(wdb + 163840 + ct * 2048 + kt * 512 + lane * 8);
        int d = nl;
        int dc = (d < WPB) ? d : WPB - 1;
        f32x4 acc = {0.f, 0.f, 0.f, 0.f};
        unsigned pb = swz(R_S4 + ((unsigned)dc << 8) + (unsigned)(kl << 4));
        const unsigned char* P = lds + pb;
        const unsigned char* Q = lds + (pb ^ 64u);
        K_HALF_AT(P, Q, 0, acc);
        int w = w0 + d;
        if (d < WPB && w < NWIN) {
            // lane holds channels ct*16+kl*4 .. +3 of window w: one dwordx4
            *(f32x4*)(out + ((size_t)bh * NBLK + (w + 1)) * DQ + ct * 16 + kl * 4) = acc;
        }
    }
#undef K_HALF_AT
}

extern "C" void kernel_launch(void* const* d_in, const int* in_sizes, int n_in,
                              void* d_out, int out_size, void* d_ws, size_t ws_size,
                              hipStream_t stream) {
    const float* kin   = (const float*)d_in[0];
    const float* pe    = (const float*)d_in[1];
    const float* wdown = (const float*)d_in[2];
    const float* wstop = (const float*)d_in[3];
    float* out = (float*)d_out;
    short* wbf  = (short*)d_ws;                       // 180224 shorts (frag-order)
    float* bias = (float*)((char*)d_ws + 360448);     // f32[2048]

    prep_kernel<<<728, 256, 0, stream>>>(wdown, wstop, pe, wbf, bias, out);
    fused_kernel<<<BQ * HQ * NWG_PER_HEAD, 512, 0, stream>>>(kin, wbf, bias, out);
}

// Round 13
// 77.664 us; speedup vs baseline: 1.3090x; 1.3068x over previous
//
#include <hip/hip_runtime.h>

// Problem constants (from reference)
#define BQ 2
#define HQ 16
#define SQ 8192
#define DQ 128
#define STR 16
#define NWIN 511     // (8192-32)/16 + 1
#define NBLK 512     // NWIN + 1 zero block
#define WPB 8        // windows per workgroup (amortizes L2 weight re-fetch)
#define NWG_PER_HEAD 64

typedef float f32x4 __attribute__((ext_vector_type(4)));
typedef short s16x8 __attribute__((ext_vector_type(8)));
typedef short s16x4 __attribute__((ext_vector_type(4)));

// LDS 53.2 KB map (all region bases multiples of 4096 -> swizzle key fields
// never perturbed by region offset):
//   kin @0     [80 rows][256B] = 20480  (4-window chunk; reused for chunk 2)
//   s0  @20480 [128][256] = 32768       (ends 53248)
//   s1  @0     [64][256]  = 16384       (kin dead after s0 chunk 2)
//   s2  @20480 [32][256]  =  8192       (s0 dead after s1)
//   s3  @0     [16][256]  =  4096       (s1 dead)
//   s4  @28672 [8][256]   =  2048       (past s2's end; s0 region dead)
#define R_KIN 0u
#define R_S0  20480u
#define R_S1  0u
#define R_S2  20480u
#define R_S3  0u
#define R_S4  28672u

// XOR swizzle keyed on 512B granule (G4/T2). Involution on global LDS byte
// offsets. HOIST SOUNDNESS (R9 proof): all B-read rows are (2nl+half) + 16m
// for integer m -> key (row>>1)&7 = nl&7 invariant over m/half; n-tile deltas
// (4096/8192/24576) and kt deltas (64..192) are pure adds into disjoint bit
// fields; bit-6 collision handled by the P/Q = P^64 pair (bit 7 of P is 0).
static __device__ __forceinline__ unsigned swz(unsigned b) {
    return b ^ (((b >> 9) & 7u) << 4);
}

static __device__ __forceinline__ short f2bf(float f) {
    __bf16 h = (__bf16)f;
    return __builtin_bit_cast(short, h);
}

// cheap silu: v_rcp_f32 instead of the exact-div sequence (~10 instrs)
static __device__ __forceinline__ float silu(float v) {
    return v * __builtin_amdgcn_rcpf(1.f + __expf(-v));
}

// ---- pass 0 (merged prep): weight permute + bias0 + zero-blocks ----
// ws: wd_bf frag-order [5 stages][8ct][8kt][512] (163840 sh) + wstop
// frag-order (16384 sh) + bias0 f32[16][128] at byte 360448.
__global__ void prep_kernel(const float* __restrict__ wd,
                            const float* __restrict__ wstop,
                            const float* __restrict__ pe,
                            short* __restrict__ o,
                            float* __restrict__ bias,
                            float* __restrict__ out) {
    int blk = blockIdx.x;
    if (blk < 704) {
        int i = blk * 256 + threadIdx.x;
        if (i < 163840) {
            int s   = i >> 15;
            int r   = i & 32767;
            int ct  = r >> 12;
            int r2  = r & 4095;
            int kt  = r2 >> 9;
            int r3  = r2 & 511;
            int ln  = r3 >> 3;
            int e   = r3 & 7;
            int ch  = ct * 16 + (ln & 15);
            int k   = kt * 32 + (ln >> 4) * 8 + e;
            o[i] = f2bf(wd[((size_t)(s * 128 + ch)) * 256 + k]);
        } else if (i < 180224) {
            int j   = i - 163840;
            int ct  = j >> 11;
            int r2  = j & 2047;
            int kt  = r2 >> 9;
            int r3  = r2 & 511;
            int ln  = r3 >> 3;
            int e   = r3 & 7;
            int ch  = ct * 16 + (ln & 15);
            int k   = kt * 32 + (ln >> 4) * 8 + e;
            o[i] = f2bf(wstop[ch * 128 + k]);
        }
    } else if (blk < 712) {
        int oo = (blk - 704) * 256 + threadIdx.x;   // 0..2047
        int j = oo >> 7;
        int c = oo & 127;
        const float* w  = wd + (size_t)c * 256;
        const float* p0 = pe + (2 * j) * DQ;
        const float* p1 = pe + (2 * j + 1) * DQ;
        float s = 0.f;
        #pragma unroll 4
        for (int i = 0; i < 128; ++i) s += w[i] * p0[i];
        #pragma unroll 4
        for (int i = 0; i < 128; ++i) s += w[i + 128] * p1[i];
        bias[oo] = s;
    } else {
        int i = (blk - 712) * 256 + threadIdx.x;  // 4096 = 32 heads * 128
        int bh = i >> 7, d = i & 127;
        out[(size_t)bh * NBLK * DQ + d] = 0.f;
    }
}

// ---- pass 1: fused compressor, WPB=8, chunked kin, R9 mechanics ----
// grid: 32 heads * 64 groups = 2048 blocks, 512 threads (8 waves).
// Wave = 16-ch tile ct for every stage. Weight fragments held in 16-reg
// half-sets; activations via b128 reads at P/Q hoisted swizzle bases.
// 53.2KB LDS -> 3 blocks/CU (24 waves); VGPR demand ~60 < (512,6) cap.
__global__ __launch_bounds__(512, 6)
void fused_kernel(const float* __restrict__ kin,
                  const short* __restrict__ wdb,
                  const float* __restrict__ bias0,
                  float* __restrict__ out) {
    __shared__ __align__(16) unsigned char lds[53248];

    const int bh = blockIdx.x >> 6;            // 0..31
    const int w0 = (blockIdx.x & 63) * WPB;    // first window of this group
    const int tid  = threadIdx.x;
    const int lane = tid & 63;
    const int ct   = tid >> 6;                 // wave = channel-tile 0..7
    const int kl   = lane >> 4;                // 0..3
    const int nl   = lane & 15;                // 0..15

    const float* kb = kin + (size_t)bh * SQ * DQ;
    const short* wbase = wdb + ct * 4096 + lane * 8;   // per-wave frag base

    // load one 80-row kin chunk (4 windows, 50% overlap), 1280 tasks
#define LOAD_KIN(cbase) {                                                      \
        _Pragma("unroll")                                                      \
        for (int it = 0; it < 3; ++it) {                                       \
            int task = tid + it * 512;                                         \
            if (task < 1280) {                                                 \
                int rr = task >> 4;                                            \
                int c8 = task & 15;                                            \
                int srow = STR * w0 + (cbase) + rr;                            \
                if (srow > SQ - 1) srow = SQ - 1;                              \
                const float* kp = kb + (size_t)srow * DQ + c8 * 8;             \
                f32x4 a0 = *(const f32x4*)kp;                                  \
                f32x4 a1 = *(const f32x4*)(kp + 4);                            \
                s16x8 v;                                                       \
                v[0]=f2bf(a0[0]); v[1]=f2bf(a0[1]); v[2]=f2bf(a0[2]); v[3]=f2bf(a0[3]); \
                v[4]=f2bf(a1[0]); v[5]=f2bf(a1[1]); v[6]=f2bf(a1[2]); v[7]=f2bf(a1[3]); \
                *(s16x8*)(lds + swz(R_KIN + (unsigned)((rr << 8) + (c8 << 4)))) = v; \
            }                                                                  \
        } }

    // 4 b128 reads (P/Q bases + immediates) + 4 MFMAs into accv
#define K_HALF_AT(P, Q, off, accv) {                                           \
        s16x8 aa0 = *(const s16x8*)((P) + (off));                              \
        s16x8 aa1 = *(const s16x8*)((Q) + (off));                              \
        s16x8 aa2 = *(const s16x8*)((P) + (off) + 128);                        \
        s16x8 aa3 = *(const s16x8*)((Q) + (off) + 128);                        \
        accv = __builtin_amdgcn_mfma_f32_16x16x32_bf16(wfh[0], aa0, accv, 0, 0, 0); \
        accv = __builtin_amdgcn_mfma_f32_16x16x32_bf16(wfh[1], aa1, accv, 0, 0, 0); \
        accv = __builtin_amdgcn_mfma_f32_16x16x32_bf16(wfh[2], aa2, accv, 0, 0, 0); \
        accv = __builtin_amdgcn_mfma_f32_16x16x32_bf16(wfh[3], aa3, accv, 0, 0, 0); }

    // silu + cvt + one ds_write_b64 of 4 consecutive channels
#define WRITE_ROW(region, d, accv) {                                           \
        s16x4 v;                                                               \
        v[0] = f2bf(silu((accv)[0])); v[1] = f2bf(silu((accv)[1]));            \
        v[2] = f2bf(silu((accv)[2])); v[3] = f2bf(silu((accv)[3]));            \
        *(s16x4*)(lds + swz((region) + ((unsigned)(d) << 8)                    \
                            + (unsigned)(ct * 32 + kl * 8))) = v; }

    const f32x4 bias = *(const f32x4*)(bias0 + nl * 128 + ct * 16 + kl * 4);

    LOAD_KIN(0);
    __syncthreads();   // kin chunk 0 ready

    // ---- stage 0, two chunks of 4 windows each; K=256 in two halves ----
    #pragma unroll
    for (int c = 0; c < 2; ++c) {
        if (c) {
            __syncthreads();   // chunk-0 kin reads retired
            LOAD_KIN(64);
            __syncthreads();   // kin chunk 1 ready
        }
        f32x4 acc0 = bias, acc1 = bias, acc2 = bias, acc3 = bias;
        #pragma unroll
        for (int half = 0; half < 2; ++half) {
            s16x8 wfh[4];
            #pragma unroll
            for (int kt = 0; kt < 4; ++kt)
                wfh[kt] = *(const s16x8*)(wbase + (half * 4 + kt) * 512);
            unsigned pb = swz(R_KIN + ((unsigned)(2 * nl + half) << 8) + (unsigned)(kl << 4));
            const unsigned char* P = lds + pb;
            const unsigned char* Q = lds + (pb ^ 64u);
            K_HALF_AT(P, Q, 0,     acc0);
            K_HALF_AT(P, Q, 4096,  acc1);
            K_HALF_AT(P, Q, 8192,  acc2);
            K_HALF_AT(P, Q, 12288, acc3);
        }
        WRITE_ROW(R_S0, c * 64 + nl,      acc0);
        WRITE_ROW(R_S0, c * 64 + 16 + nl, acc1);
        WRITE_ROW(R_S0, c * 64 + 32 + nl, acc2);
        WRITE_ROW(R_S0, c * 64 + 48 + nl, acc3);
    }
    __syncthreads();   // s0 (128 rows) complete; kin dead

    // ---- stage 1: 128 in rows -> 64 out rows (4 n-tiles, deltas +8192) ----
    {
        f32x4 acc0 = {}, acc1 = {}, acc2 = {}, acc3 = {};
        #pragma unroll
        for (int half = 0; half < 2; ++half) {
            s16x8 wfh[4];
            #pragma unroll
            for (int kt = 0; kt < 4; ++kt)
                wfh[kt] = *(const s16x8*)(wbase + 32768 + (half * 4 + kt) * 512);
            unsigned pb = swz(R_S0 + ((unsigned)(2 * nl + half) << 8) + (unsigned)(kl << 4));
            const unsigned char* P = lds + pb;
            const unsigned char* Q = lds + (pb ^ 64u);
            K_HALF_AT(P, Q, 0,     acc0);
            K_HALF_AT(P, Q, 8192,  acc1);
            K_HALF_AT(P, Q, 16384, acc2);
            K_HALF_AT(P, Q, 24576, acc3);
        }
        WRITE_ROW(R_S1, nl,      acc0);
        WRITE_ROW(R_S1, 16 + nl, acc1);
        WRITE_ROW(R_S1, 32 + nl, acc2);
        WRITE_ROW(R_S1, 48 + nl, acc3);
    }
    __syncthreads();   // s1 (64 rows); s0 dead

    // ---- stage 2: 64 -> 32 rows (2 n-tiles) ----
    {
        f32x4 acc0 = {}, acc1 = {};
        #pragma unroll
        for (int half = 0; half < 2; ++half) {
            s16x8 wfh[4];
            #pragma unroll
            for (int kt = 0; kt < 4; ++kt)
                wfh[kt] = *(const s16x8*)(wbase + 2 * 32768 + (half * 4 + kt) * 512);
            unsigned pb = swz(R_S1 + ((unsigned)(2 * nl + half) << 8) + (unsigned)(kl << 4));
            const unsigned char* P = lds + pb;
            const unsigned char* Q = lds + (pb ^ 64u);
            K_HALF_AT(P, Q, 0,    acc0);
            K_HALF_AT(P, Q, 8192, acc1);
        }
        WRITE_ROW(R_S2, nl,      acc0);
        WRITE_ROW(R_S2, 16 + nl, acc1);
    }
    __syncthreads();   // s2 (32 rows); s1 dead

    // ---- stage 3: 32 -> 16 rows ----
    {
        f32x4 acc0 = {};
        #pragma unroll
        for (int half = 0; half < 2; ++half) {
            s16x8 wfh[4];
            #pragma unroll
            for (int kt = 0; kt < 4; ++kt)
                wfh[kt] = *(const s16x8*)(wbase + 3 * 32768 + (half * 4 + kt) * 512);
            unsigned pb = swz(R_S2 + ((unsigned)(2 * nl + half) << 8) + (unsigned)(kl << 4));
            const unsigned char* P = lds + pb;
            const unsigned char* Q = lds + (pb ^ 64u);
            K_HALF_AT(P, Q, 0, acc0);
        }
        WRITE_ROW(R_S3, nl, acc0);
    }
    __syncthreads();   // s3 (16 rows); s2 dead

    // ---- stage 4: 16 -> 8 rows (lanes nl>=8 idle/clamped) ----
    {
        int dc = (nl < 8) ? nl : 7;
        f32x4 acc0 = {};
        #pragma unroll
        for (int half = 0; half < 2; ++half) {
            s16x8 wfh[4];
            #pragma unroll
            for (int kt = 0; kt < 4; ++kt)
                wfh[kt] = *(const s16x8*)(wbase + 4 * 32768 + (half * 4 + kt) * 512);
            unsigned pb = swz(R_S3 + ((unsigned)(2 * dc + half) << 8) + (unsigned)(kl << 4));
            const unsigned char* P = lds + pb;
            const unsigned char* Q = lds + (pb ^ 64u);
            K_HALF_AT(P, Q, 0, acc0);
        }
        if (nl < 8) WRITE_ROW(R_S4, nl, acc0);
    }
    __syncthreads();   // s4 (8 rows)

    // ---- w_stop: 8 rows, K=128, no activation -> global f32 ----
    {
        s16x8 wfh[4];
        #pragma unroll
        for (int kt = 0; kt < 4; ++kt)
            wfh[kt] = *(const s16x8*)(wdb + 163840 + ct * 2048 + kt * 512 + lane * 8);
        int dc = (nl < 8) ? nl : 7;
        f32x4 acc = {0.f, 0.f, 0.f, 0.f};
        unsigned pb = swz(R_S4 + ((unsigned)dc << 8) + (unsigned)(kl << 4));
        const unsigned char* P = lds + pb;
        const unsigned char* Q = lds + (pb ^ 64u);
        K_HALF_AT(P, Q, 0, acc);
        int w = w0 + nl;
        if (nl < 8 && w < NWIN) {
            // lane holds channels ct*16+kl*4 .. +3 of window w: one dwordx4
            *(f32x4*)(out + ((size_t)bh * NBLK + (w + 1)) * DQ + ct * 16 + kl * 4) = acc;
        }
    }
#undef K_HALF_AT
#undef WRITE_ROW
#undef LOAD_KIN
}

extern "C" void kernel_launch(void* const* d_in, const int* in_sizes, int n_in,
                              void* d_out, int out_size, void* d_ws, size_t ws_size,
                              hipStream_t stream) {
    const float* kin   = (const float*)d_in[0];
    const float* pe    = (const float*)d_in[1];
    const float* wdown = (const float*)d_in[2];
    const float* wstop = (const float*)d_in[3];
    float* out = (float*)d_out;
    short* wbf  = (short*)d_ws;                       // 180224 shorts (frag-order)
    float* bias = (float*)((char*)d_ws + 360448);     // f32[2048]

    prep_kernel<<<728, 256, 0, stream>>>(wdown, wstop, pe, wbf, bias, out);
    fused_kernel<<<BQ * HQ * NWG_PER_HEAD, 512, 0, stream>>>(kin, wbf, bias, out);
}

// Round 14
// 77.204 us; speedup vs baseline: 1.3168x; 1.0060x over previous
//
#include <hip/hip_runtime.h>

// Problem constants (from reference)
#define BQ 2
#define HQ 16
#define SQ 8192
#define DQ 128
#define STR 16
#define NWIN 511     // (8192-32)/16 + 1
#define NBLK 512     // NWIN + 1 zero block
#define WPB 8        // windows per workgroup (amortizes L2 weight re-fetch)
#define NWG_PER_HEAD 64

typedef float f32x4 __attribute__((ext_vector_type(4)));
typedef short s16x8 __attribute__((ext_vector_type(8)));
typedef short s16x4 __attribute__((ext_vector_type(4)));

// LDS 53.2 KB map (all region bases multiples of 4096 -> swizzle key fields
// never perturbed by region offset):
//   kin @0     [80 rows][256B] = 20480  (4-window chunk; reused for chunk 2)
//   s0  @20480 [128][256] = 32768       (ends 53248)
//   s1  @0     [64][256]  = 16384       (kin dead after s0 chunk 2)
//   s2  @20480 [32][256]  =  8192       (s0 dead after s1)
//   s3  @0     [16][256]  =  4096       (s1 dead)
//   s4  @28672 [8][256]   =  2048       (past s2's end; s0 region dead)
#define R_KIN 0u
#define R_S0  20480u
#define R_S1  0u
#define R_S2  20480u
#define R_S3  0u
#define R_S4  28672u

// XOR swizzle keyed on 512B granule (G4/T2). Involution on global LDS byte
// offsets. HOIST SOUNDNESS (R9 proof): all B-read rows are (2nl+half)+16m ->
// key (row>>1)&7 = nl&7 invariant over m/half; n-tile deltas (4096..24576)
// and kt deltas (64..192) are adds into disjoint bit fields; bit-6 collision
// handled by the P/Q = P^64 pair (bit 7 of P is 0). HALF FOLD (new): row is
// even at half=0 -> bit 8 of P is 0 -> half=1 is P+256 carry-free, so ONE
// swz serves the whole stage; all reads are P/Q + compile-time immediates.
static __device__ __forceinline__ unsigned swz(unsigned b) {
    return b ^ (((b >> 9) & 7u) << 4);
}

static __device__ __forceinline__ short f2bf(float f) {
    __bf16 h = (__bf16)f;
    return __builtin_bit_cast(short, h);
}

// cheap silu: v_rcp_f32 instead of the exact-div sequence (~10 instrs)
static __device__ __forceinline__ float silu(float v) {
    return v * __builtin_amdgcn_rcpf(1.f + __expf(-v));
}

// ---- pass 0 (merged prep): weight permute + bias0 + zero-blocks ----
// ws: wd_bf frag-order [5 stages][8ct][8kt][512] (163840 sh) + wstop
// frag-order (16384 sh) + bias0 f32[16][128] at byte 360448.
__global__ void prep_kernel(const float* __restrict__ wd,
                            const float* __restrict__ wstop,
                            const float* __restrict__ pe,
                            short* __restrict__ o,
                            float* __restrict__ bias,
                            float* __restrict__ out) {
    int blk = blockIdx.x;
    if (blk < 704) {
        int i = blk * 256 + threadIdx.x;
        if (i < 163840) {
            int s   = i >> 15;
            int r   = i & 32767;
            int ct  = r >> 12;
            int r2  = r & 4095;
            int kt  = r2 >> 9;
            int r3  = r2 & 511;
            int ln  = r3 >> 3;
            int e   = r3 & 7;
            int ch  = ct * 16 + (ln & 15);
            int k   = kt * 32 + (ln >> 4) * 8 + e;
            o[i] = f2bf(wd[((size_t)(s * 128 + ch)) * 256 + k]);
        } else if (i < 180224) {
            int j   = i - 163840;
            int ct  = j >> 11;
            int r2  = j & 2047;
            int kt  = r2 >> 9;
            int r3  = r2 & 511;
            int ln  = r3 >> 3;
            int e   = r3 & 7;
            int ch  = ct * 16 + (ln & 15);
            int k   = kt * 32 + (ln >> 4) * 8 + e;
            o[i] = f2bf(wstop[ch * 128 + k]);
        }
    } else if (blk < 712) {
        int oo = (blk - 704) * 256 + threadIdx.x;   // 0..2047
        int j = oo >> 7;
        int c = oo & 127;
        const float* w  = wd + (size_t)c * 256;
        const float* p0 = pe + (2 * j) * DQ;
        const float* p1 = pe + (2 * j + 1) * DQ;
        float s = 0.f;
        #pragma unroll 4
        for (int i = 0; i < 128; ++i) s += w[i] * p0[i];
        #pragma unroll 4
        for (int i = 0; i < 128; ++i) s += w[i + 128] * p1[i];
        bias[oo] = s;
    } else {
        int i = (blk - 712) * 256 + threadIdx.x;  // 4096 = 32 heads * 128
        int bh = i >> 7, d = i & 127;
        out[(size_t)bh * NBLK * DQ + d] = 0.f;
    }
}

// ---- pass 1: fused compressor, WPB=8, latency-hidden loads ----
// Weight prefetch chain: one wf[8] set; stage s+1's frags issued before the
// stage-s ending barrier. kin chunk 1 async-split (T14): loads issued before
// chunk-0 compute, written after the reads-retired barrier. One swz/stage.
// 53.2KB LDS -> 3 blocks/CU; VGPR ~76 < 85 cap at (512,6).
__global__ __launch_bounds__(512, 6)
void fused_kernel(const float* __restrict__ kin,
                  const short* __restrict__ wdb,
                  const float* __restrict__ bias0,
                  float* __restrict__ out) {
    __shared__ __align__(16) unsigned char lds[53248];

    const int bh = blockIdx.x >> 6;            // 0..31
    const int w0 = (blockIdx.x & 63) * WPB;    // first window of this group
    const int tid  = threadIdx.x;
    const int lane = tid & 63;
    const int ct   = tid >> 6;                 // wave = channel-tile 0..7
    const int kl   = lane >> 4;                // 0..3
    const int nl   = lane & 15;                // 0..15

    const float* kb = kin + (size_t)bh * SQ * DQ;
    const short* wbase = wdb + ct * 4096 + lane * 8;   // per-wave frag base

    // 4 b128 reads (P/Q + immediates) + 4 MFMAs with explicit frags
#define K_HALF4(W0, W1, W2, W3, P, Q, off, accv) {                             \
        s16x8 aa0 = *(const s16x8*)((P) + (off));                              \
        s16x8 aa1 = *(const s16x8*)((Q) + (off));                              \
        s16x8 aa2 = *(const s16x8*)((P) + (off) + 128);                        \
        s16x8 aa3 = *(const s16x8*)((Q) + (off) + 128);                        \
        accv = __builtin_amdgcn_mfma_f32_16x16x32_bf16(W0, aa0, accv, 0, 0, 0); \
        accv = __builtin_amdgcn_mfma_f32_16x16x32_bf16(W1, aa1, accv, 0, 0, 0); \
        accv = __builtin_amdgcn_mfma_f32_16x16x32_bf16(W2, aa2, accv, 0, 0, 0); \
        accv = __builtin_amdgcn_mfma_f32_16x16x32_bf16(W3, aa3, accv, 0, 0, 0); }

    // both K-halves of one n-tile (half delta = +256, carry-free)
#define K_FULL(P, Q, off, accv)                                                \
        K_HALF4(wf[0], wf[1], wf[2], wf[3], P, Q, (off),       accv)           \
        K_HALF4(wf[4], wf[5], wf[6], wf[7], P, Q, (off) + 256, accv)

    // silu + cvt + one ds_write_b64 of 4 consecutive channels
#define WRITE_ROW(region, d, accv) {                                           \
        s16x4 v;                                                               \
        v[0] = f2bf(silu((accv)[0])); v[1] = f2bf(silu((accv)[1]));            \
        v[2] = f2bf(silu((accv)[2])); v[3] = f2bf(silu((accv)[3]));            \
        *(s16x4*)(lds + swz((region) + ((unsigned)(d) << 8)                    \
                            + (unsigned)(ct * 32 + kl * 8))) = v; }

#define LOAD_WF(stage_off) {                                                   \
        _Pragma("unroll")                                                      \
        for (int kt = 0; kt < 8; ++kt)                                         \
            wf[kt] = *(const s16x8*)(wbase + (stage_off) + kt * 512); }

    // stage-0 weights issued first: latency overlaps phase A
    s16x8 wf[8];
    LOAD_WF(0);
    const f32x4 bias = *(const f32x4*)(bias0 + nl * 128 + ct * 16 + kl * 4);

    // ---- phase A: kin chunk 0 (80 rows x 16 chunks = 1280 tasks) ----
    #pragma unroll
    for (int it = 0; it < 3; ++it) {
        int task = tid + it * 512;
        if (task < 1280) {
            int rr = task >> 4;
            int c8 = task & 15;
            int srow = STR * w0 + rr;
            if (srow > SQ - 1) srow = SQ - 1;
            const float* kp = kb + (size_t)srow * DQ + c8 * 8;
            f32x4 a0 = *(const f32x4*)kp;
            f32x4 a1 = *(const f32x4*)(kp + 4);
            s16x8 v;
            v[0]=f2bf(a0[0]); v[1]=f2bf(a0[1]); v[2]=f2bf(a0[2]); v[3]=f2bf(a0[3]);
            v[4]=f2bf(a1[0]); v[5]=f2bf(a1[1]); v[6]=f2bf(a1[2]); v[7]=f2bf(a1[3]);
            *(s16x8*)(lds + swz(R_KIN + (unsigned)((rr << 8) + (c8 << 4)))) = v;
        }
    }
    __syncthreads();   // B1: chunk 0 ready

    // ---- async prefetch of chunk-1 rows 0..63 (2 tasks/thread, 16 regs) ----
    f32x4 pA0, pA1, pB0, pB1;
    const int prow = tid >> 4, pc8 = tid & 15;
    {
        int sr = STR * w0 + 64 + prow;                 // rows 0..31 of chunk 1
        if (sr > SQ - 1) sr = SQ - 1;
        const float* kp = kb + (size_t)sr * DQ + pc8 * 8;
        pA0 = *(const f32x4*)kp; pA1 = *(const f32x4*)(kp + 4);
        sr = STR * w0 + 96 + prow;                     // rows 32..63
        if (sr > SQ - 1) sr = SQ - 1;
        kp = kb + (size_t)sr * DQ + pc8 * 8;
        pB0 = *(const f32x4*)kp; pB1 = *(const f32x4*)(kp + 4);
    }

    // stage-0 P/Q (constant across chunks; one swz for the whole stage)
    unsigned pb0 = swz(R_KIN + ((unsigned)(2 * nl) << 8) + (unsigned)(kl << 4));
    const unsigned char* P0 = lds + pb0;
    const unsigned char* Q0 = lds + (pb0 ^ 64u);

    // ---- stage 0, chunk 0 (windows 0..3 -> s0 rows 0..63) ----
    {
        f32x4 acc0 = bias, acc1 = bias, acc2 = bias, acc3 = bias;
        K_FULL(P0, Q0, 0,     acc0);
        K_FULL(P0, Q0, 4096,  acc1);
        K_FULL(P0, Q0, 8192,  acc2);
        K_FULL(P0, Q0, 12288, acc3);
        WRITE_ROW(R_S0, nl,      acc0);
        WRITE_ROW(R_S0, 16 + nl, acc1);
        WRITE_ROW(R_S0, 32 + nl, acc2);
        WRITE_ROW(R_S0, 48 + nl, acc3);
    }
    __syncthreads();   // B2: chunk-0 kin reads retired

    // ---- write prefetched chunk-1 rows; late-load rows 64..79 ----
    {
        s16x8 v;
        v[0]=f2bf(pA0[0]); v[1]=f2bf(pA0[1]); v[2]=f2bf(pA0[2]); v[3]=f2bf(pA0[3]);
        v[4]=f2bf(pA1[0]); v[5]=f2bf(pA1[1]); v[6]=f2bf(pA1[2]); v[7]=f2bf(pA1[3]);
        *(s16x8*)(lds + swz(R_KIN + (unsigned)((prow << 8) + (pc8 << 4)))) = v;
        v[0]=f2bf(pB0[0]); v[1]=f2bf(pB0[1]); v[2]=f2bf(pB0[2]); v[3]=f2bf(pB0[3]);
        v[4]=f2bf(pB1[0]); v[5]=f2bf(pB1[1]); v[6]=f2bf(pB1[2]); v[7]=f2bf(pB1[3]);
        *(s16x8*)(lds + swz(R_KIN + (unsigned)(((32 + prow) << 8) + (pc8 << 4)))) = v;
        if (tid < 256) {
            int rr = 64 + (tid >> 4);
            int c8 = tid & 15;
            int sr = STR * w0 + 64 + rr;
            if (sr > SQ - 1) sr = SQ - 1;
            const float* kp = kb + (size_t)sr * DQ + c8 * 8;
            f32x4 a0 = *(const f32x4*)kp;
            f32x4 a1 = *(const f32x4*)(kp + 4);
            v[0]=f2bf(a0[0]); v[1]=f2bf(a0[1]); v[2]=f2bf(a0[2]); v[3]=f2bf(a0[3]);
            v[4]=f2bf(a1[0]); v[5]=f2bf(a1[1]); v[6]=f2bf(a1[2]); v[7]=f2bf(a1[3]);
            *(s16x8*)(lds + swz(R_KIN + (unsigned)((rr << 8) + (c8 << 4)))) = v;
        }
    }
    __syncthreads();   // B3: chunk 1 ready

    // ---- stage 0, chunk 1 (windows 4..7 -> s0 rows 64..127) ----
    {
        f32x4 acc0 = bias, acc1 = bias, acc2 = bias, acc3 = bias;
        K_FULL(P0, Q0, 0,     acc0);
        K_FULL(P0, Q0, 4096,  acc1);
        K_FULL(P0, Q0, 8192,  acc2);
        K_FULL(P0, Q0, 12288, acc3);
        LOAD_WF(32768);   // prefetch stage-1 weights across the barrier
        WRITE_ROW(R_S0, 64 + nl,  acc0);
        WRITE_ROW(R_S0, 80 + nl,  acc1);
        WRITE_ROW(R_S0, 96 + nl,  acc2);
        WRITE_ROW(R_S0, 112 + nl, acc3);
    }
    __syncthreads();   // B4: s0 complete; kin dead

    // ---- stage 1: 128 -> 64 rows (4 n-tiles, deltas +8192) ----
    {
        unsigned pb = swz(R_S0 + ((unsigned)(2 * nl) << 8) + (unsigned)(kl << 4));
        const unsigned char* P = lds + pb;
        const unsigned char* Q = lds + (pb ^ 64u);
        f32x4 acc0 = {}, acc1 = {}, acc2 = {}, acc3 = {};
        K_FULL(P, Q, 0,     acc0);
        K_FULL(P, Q, 8192,  acc1);
        K_FULL(P, Q, 16384, acc2);
        K_FULL(P, Q, 24576, acc3);
        LOAD_WF(2 * 32768);
        WRITE_ROW(R_S1, nl,      acc0);
        WRITE_ROW(R_S1, 16 + nl, acc1);
        WRITE_ROW(R_S1, 32 + nl, acc2);
        WRITE_ROW(R_S1, 48 + nl, acc3);
    }
    __syncthreads();   // s1 done; s0 dead

    // ---- stage 2: 64 -> 32 rows ----
    {
        unsigned pb = swz(R_S1 + ((unsigned)(2 * nl) << 8) + (unsigned)(kl << 4));
        const unsigned char* P = lds + pb;
        const unsigned char* Q = lds + (pb ^ 64u);
        f32x4 acc0 = {}, acc1 = {};
        K_FULL(P, Q, 0,    acc0);
        K_FULL(P, Q, 8192, acc1);
        LOAD_WF(3 * 32768);
        WRITE_ROW(R_S2, nl,      acc0);
        WRITE_ROW(R_S2, 16 + nl, acc1);
    }
    __syncthreads();   // s2 done; s1 dead

    // ---- stage 3: 32 -> 16 rows ----
    {
        unsigned pb = swz(R_S2 + ((unsigned)(2 * nl) << 8) + (unsigned)(kl << 4));
        const unsigned char* P = lds + pb;
        const unsigned char* Q = lds + (pb ^ 64u);
        f32x4 acc0 = {};
        K_FULL(P, Q, 0, acc0);
        LOAD_WF(4 * 32768);
        WRITE_ROW(R_S3, nl, acc0);
    }
    __syncthreads();   // s3 done; s2 dead

    // ---- stage 4: 16 -> 8 rows (lanes nl>=8 clamped) ----
    {
        int dc = (nl < 8) ? nl : 7;
        unsigned pb = swz(R_S3 + ((unsigned)(2 * dc) << 8) + (unsigned)(kl << 4));
        const unsigned char* P = lds + pb;
        const unsigned char* Q = lds + (pb ^ 64u);
        f32x4 acc0 = {};
        K_FULL(P, Q, 0, acc0);
        // prefetch w_stop (4 frags) across the barrier
        #pragma unroll
        for (int kt = 0; kt < 4; ++kt)
            wf[kt] = *(const s16x8*)(wdb + 163840 + ct * 2048 + kt * 512 + lane * 8);
        if (nl < 8) WRITE_ROW(R_S4, nl, acc0);
    }
    __syncthreads();   // s4 done

    // ---- w_stop: 8 rows, K=128, no activation -> global f32 ----
    {
        int dc = (nl < 8) ? nl : 7;
        unsigned pb = swz(R_S4 + ((unsigned)dc << 8) + (unsigned)(kl << 4));
        const unsigned char* P = lds + pb;
        const unsigned char* Q = lds + (pb ^ 64u);
        f32x4 acc = {0.f, 0.f, 0.f, 0.f};
        K_HALF4(wf[0], wf[1], wf[2], wf[3], P, Q, 0, acc);
        int w = w0 + nl;
        if (nl < 8 && w < NWIN) {
            // lane holds channels ct*16+kl*4 .. +3 of window w: one dwordx4
            *(f32x4*)(out + ((size_t)bh * NBLK + (w + 1)) * DQ + ct * 16 + kl * 4) = acc;
        }
    }
#undef K_HALF4
#undef K_FULL
#undef WRITE_ROW
#undef LOAD_WF
}

extern "C" void kernel_launch(void* const* d_in, const int* in_sizes, int n_in,
                              void* d_out, int out_size, void* d_ws, size_t ws_size,
                              hipStream_t stream) {
    const float* kin   = (const float*)d_in[0];
    const float* pe    = (const float*)d_in[1];
    const float* wdown = (const float*)d_in[2];
    const float* wstop = (const float*)d_in[3];
    float* out = (float*)d_out;
    short* wbf  = (short*)d_ws;                       // 180224 shorts (frag-order)
    float* bias = (float*)((char*)d_ws + 360448);     // f32[2048]

    prep_kernel<<<728, 256, 0, stream>>>(wdown, wstop, pe, wbf, bias, out);
    fused_kernel<<<BQ * HQ * NWG_PER_HEAD, 512, 0, stream>>>(kin, wbf, bias, out);
}

// Round 15
// 76.487 us; speedup vs baseline: 1.3291x; 1.0094x over previous
//
#include <hip/hip_runtime.h>

// Problem constants (from reference)
#define BQ 2
#define HQ 16
#define SQ 8192
#define DQ 128
#define STR 16
#define NWIN 511     // (8192-32)/16 + 1
#define NBLK 512     // NWIN + 1 zero block
#define WPB 8        // windows per workgroup (amortizes L2 weight re-fetch)
#define NWG_PER_HEAD 64

typedef float f32x4 __attribute__((ext_vector_type(4)));
typedef short s16x8 __attribute__((ext_vector_type(8)));
typedef short s16x4 __attribute__((ext_vector_type(4)));

// LDS 53.2 KB map (all region bases multiples of 4096 -> swizzle key fields
// never perturbed by region offset):
//   kin @0     [80 rows][256B] = 20480  (4-window chunk; reused for chunk 2)
//   s0  @20480 [128][256] = 32768       (ends 53248)
//   s1  @0     [64][256]  = 16384       (kin dead after s0 chunk 2)
//   s2  @20480 [32][256]  =  8192       (s0 dead after s1)
//   s3  @0     [16][256]  =  4096       (s1 dead)
//   s4  @28672 [8][256]   =  2048       (past s2's end; s0 region dead)
#define R_KIN 0u
#define R_S0  20480u
#define R_S1  0u
#define R_S2  20480u
#define R_S3  0u
#define R_S4  28672u

// XOR swizzle keyed on 512B granule (G4/T2). Involution on global LDS byte
// offsets. HOIST SOUNDNESS (R9 proof): all B-read rows are (2nl+half)+16m ->
// key (row>>1)&7 = nl&7 invariant over m/half; n-tile deltas (4096..24576)
// and kt deltas (64..192) are adds into disjoint bit fields; bit-6 collision
// handled by the P/Q = P^64 pair (bit 7 of P is 0). HALF FOLD: row is even at
// half=0 -> bit 8 of P is 0 -> half=1 is P+256 carry-free, so ONE swz serves
// the whole stage; all reads are P/Q + compile-time immediates.
static __device__ __forceinline__ unsigned swz(unsigned b) {
    return b ^ (((b >> 9) & 7u) << 4);
}

static __device__ __forceinline__ short f2bf(float f) {
    __bf16 h = (__bf16)f;
    return __builtin_bit_cast(short, h);
}

// cheap silu: v_rcp_f32 instead of the exact-div sequence (~10 instrs)
static __device__ __forceinline__ float silu(float v) {
    return v * __builtin_amdgcn_rcpf(1.f + __expf(-v));
}

// ---- pass 0 (merged prep): weight permute + bias0 + zero-blocks ----
// ws: wd_bf frag-order [5 stages][8ct][8kt][512] (163840 sh) + wstop
// frag-order (16384 sh) + bias0 f32[16][128] at byte 360448.
__global__ void prep_kernel(const float* __restrict__ wd,
                            const float* __restrict__ wstop,
                            const float* __restrict__ pe,
                            short* __restrict__ o,
                            float* __restrict__ bias,
                            float* __restrict__ out) {
    int blk = blockIdx.x;
    if (blk < 704) {
        int i = blk * 256 + threadIdx.x;
        if (i < 163840) {
            int s   = i >> 15;
            int r   = i & 32767;
            int ct  = r >> 12;
            int r2  = r & 4095;
            int kt  = r2 >> 9;
            int r3  = r2 & 511;
            int ln  = r3 >> 3;
            int e   = r3 & 7;
            int ch  = ct * 16 + (ln & 15);
            int k   = kt * 32 + (ln >> 4) * 8 + e;
            o[i] = f2bf(wd[((size_t)(s * 128 + ch)) * 256 + k]);
        } else if (i < 180224) {
            int j   = i - 163840;
            int ct  = j >> 11;
            int r2  = j & 2047;
            int kt  = r2 >> 9;
            int r3  = r2 & 511;
            int ln  = r3 >> 3;
            int e   = r3 & 7;
            int ch  = ct * 16 + (ln & 15);
            int k   = kt * 32 + (ln >> 4) * 8 + e;
            o[i] = f2bf(wstop[ch * 128 + k]);
        }
    } else if (blk < 712) {
        int oo = (blk - 704) * 256 + threadIdx.x;   // 0..2047
        int j = oo >> 7;
        int c = oo & 127;
        const float* w  = wd + (size_t)c * 256;
        const float* p0 = pe + (2 * j) * DQ;
        const float* p1 = pe + (2 * j + 1) * DQ;
        float s = 0.f;
        #pragma unroll 4
        for (int i = 0; i < 128; ++i) s += w[i] * p0[i];
        #pragma unroll 4
        for (int i = 0; i < 128; ++i) s += w[i + 128] * p1[i];
        bias[oo] = s;
    } else {
        int i = (blk - 712) * 256 + threadIdx.x;  // 4096 = 32 heads * 128
        int bh = i >> 7, d = i & 127;
        out[(size_t)bh * NBLK * DQ + d] = 0.f;
    }
}

// ---- pass 1: fused compressor, WPB=8 ----
// Weight prefetch chain (R14 move 1): one wf[8] set; stage s+1's frags issued
// before the stage-s ending barrier. One swz per stage (move 3). kin chunk 1
// loaded directly between barriers (R14's reg-prefetch spilled - move 2 drop).
// 53.2KB LDS -> 3 blocks/CU; spill-free at (512,6).
__global__ __launch_bounds__(512, 6)
void fused_kernel(const float* __restrict__ kin,
                  const short* __restrict__ wdb,
                  const float* __restrict__ bias0,
                  float* __restrict__ out) {
    __shared__ __align__(16) unsigned char lds[53248];

    const int bh = blockIdx.x >> 6;            // 0..31
    const int w0 = (blockIdx.x & 63) * WPB;    // first window of this group
    const int tid  = threadIdx.x;
    const int lane = tid & 63;
    const int ct   = tid >> 6;                 // wave = channel-tile 0..7
    const int kl   = lane >> 4;                // 0..3
    const int nl   = lane & 15;                // 0..15

    const float* kb = kin + (size_t)bh * SQ * DQ;
    const short* wbase = wdb + ct * 4096 + lane * 8;   // per-wave frag base

    // load one 80-row kin chunk (4 windows, 50% overlap), 1280 tasks
#define LOAD_KIN(cbase) {                                                      \
        _Pragma("unroll")                                                      \
        for (int it = 0; it < 3; ++it) {                                       \
            int task = tid + it * 512;                                         \
            if (task < 1280) {                                                 \
                int rr = task >> 4;                                            \
                int c8 = task & 15;                                            \
                int srow = STR * w0 + (cbase) + rr;                            \
                if (srow > SQ - 1) srow = SQ - 1;                              \
                const float* kp = kb + (size_t)srow * DQ + c8 * 8;             \
                f32x4 a0 = *(const f32x4*)kp;                                  \
                f32x4 a1 = *(const f32x4*)(kp + 4);                            \
                s16x8 v;                                                       \
                v[0]=f2bf(a0[0]); v[1]=f2bf(a0[1]); v[2]=f2bf(a0[2]); v[3]=f2bf(a0[3]); \
                v[4]=f2bf(a1[0]); v[5]=f2bf(a1[1]); v[6]=f2bf(a1[2]); v[7]=f2bf(a1[3]); \
                *(s16x8*)(lds + swz(R_KIN + (unsigned)((rr << 8) + (c8 << 4)))) = v; \
            }                                                                  \
        } }

    // 4 b128 reads (P/Q + immediates) + 4 MFMAs with explicit frags
#define K_HALF4(W0, W1, W2, W3, P, Q, off, accv) {                             \
        s16x8 aa0 = *(const s16x8*)((P) + (off));                              \
        s16x8 aa1 = *(const s16x8*)((Q) + (off));                              \
        s16x8 aa2 = *(const s16x8*)((P) + (off) + 128);                        \
        s16x8 aa3 = *(const s16x8*)((Q) + (off) + 128);                        \
        accv = __builtin_amdgcn_mfma_f32_16x16x32_bf16(W0, aa0, accv, 0, 0, 0); \
        accv = __builtin_amdgcn_mfma_f32_16x16x32_bf16(W1, aa1, accv, 0, 0, 0); \
        accv = __builtin_amdgcn_mfma_f32_16x16x32_bf16(W2, aa2, accv, 0, 0, 0); \
        accv = __builtin_amdgcn_mfma_f32_16x16x32_bf16(W3, aa3, accv, 0, 0, 0); }

    // both K-halves of one n-tile (half delta = +256, carry-free)
#define K_FULL(P, Q, off, accv)                                                \
        K_HALF4(wf[0], wf[1], wf[2], wf[3], P, Q, (off),       accv)           \
        K_HALF4(wf[4], wf[5], wf[6], wf[7], P, Q, (off) + 256, accv)

    // silu + cvt + one ds_write_b64 of 4 consecutive channels
#define WRITE_ROW(region, d, accv) {                                           \
        s16x4 v;                                                               \
        v[0] = f2bf(silu((accv)[0])); v[1] = f2bf(silu((accv)[1]));            \
        v[2] = f2bf(silu((accv)[2])); v[3] = f2bf(silu((accv)[3]));            \
        *(s16x4*)(lds + swz((region) + ((unsigned)(d) << 8)                    \
                            + (unsigned)(ct * 32 + kl * 8))) = v; }

#define LOAD_WF(stage_off) {                                                   \
        _Pragma("unroll")                                                      \
        for (int kt = 0; kt < 8; ++kt)                                         \
            wf[kt] = *(const s16x8*)(wbase + (stage_off) + kt * 512); }

    // stage-0 weights issued first: latency overlaps phase A
    s16x8 wf[8];
    LOAD_WF(0);
    const f32x4 bias = *(const f32x4*)(bias0 + nl * 128 + ct * 16 + kl * 4);

    LOAD_KIN(0);
    __syncthreads();   // B1: chunk 0 ready

    // stage-0 P/Q (constant across chunks; one swz for the whole stage)
    unsigned pb0 = swz(R_KIN + ((unsigned)(2 * nl) << 8) + (unsigned)(kl << 4));
    const unsigned char* P0 = lds + pb0;
    const unsigned char* Q0 = lds + (pb0 ^ 64u);

    // ---- stage 0, chunk 0 (windows 0..3 -> s0 rows 0..63) ----
    {
        f32x4 acc0 = bias, acc1 = bias, acc2 = bias, acc3 = bias;
        K_FULL(P0, Q0, 0,     acc0);
        K_FULL(P0, Q0, 4096,  acc1);
        K_FULL(P0, Q0, 8192,  acc2);
        K_FULL(P0, Q0, 12288, acc3);
        WRITE_ROW(R_S0, nl,      acc0);
        WRITE_ROW(R_S0, 16 + nl, acc1);
        WRITE_ROW(R_S0, 32 + nl, acc2);
        WRITE_ROW(R_S0, 48 + nl, acc3);
    }
    __syncthreads();   // B2: chunk-0 kin reads retired

    LOAD_KIN(64);      // chunk 1 (windows 4..7)
    __syncthreads();   // B3: chunk 1 ready

    // ---- stage 0, chunk 1 (windows 4..7 -> s0 rows 64..127) ----
    {
        f32x4 acc0 = bias, acc1 = bias, acc2 = bias, acc3 = bias;
        K_FULL(P0, Q0, 0,     acc0);
        K_FULL(P0, Q0, 4096,  acc1);
        K_FULL(P0, Q0, 8192,  acc2);
        K_FULL(P0, Q0, 12288, acc3);
        LOAD_WF(32768);   // prefetch stage-1 weights across the barrier
        WRITE_ROW(R_S0, 64 + nl,  acc0);
        WRITE_ROW(R_S0, 80 + nl,  acc1);
        WRITE_ROW(R_S0, 96 + nl,  acc2);
        WRITE_ROW(R_S0, 112 + nl, acc3);
    }
    __syncthreads();   // B4: s0 complete; kin dead

    // ---- stage 1: 128 -> 64 rows (4 n-tiles, deltas +8192) ----
    {
        unsigned pb = swz(R_S0 + ((unsigned)(2 * nl) << 8) + (unsigned)(kl << 4));
        const unsigned char* P = lds + pb;
        const unsigned char* Q = lds + (pb ^ 64u);
        f32x4 acc0 = {}, acc1 = {}, acc2 = {}, acc3 = {};
        K_FULL(P, Q, 0,     acc0);
        K_FULL(P, Q, 8192,  acc1);
        K_FULL(P, Q, 16384, acc2);
        K_FULL(P, Q, 24576, acc3);
        LOAD_WF(2 * 32768);
        WRITE_ROW(R_S1, nl,      acc0);
        WRITE_ROW(R_S1, 16 + nl, acc1);
        WRITE_ROW(R_S1, 32 + nl, acc2);
        WRITE_ROW(R_S1, 48 + nl, acc3);
    }
    __syncthreads();   // s1 done; s0 dead

    // ---- stage 2: 64 -> 32 rows ----
    {
        unsigned pb = swz(R_S1 + ((unsigned)(2 * nl) << 8) + (unsigned)(kl << 4));
        const unsigned char* P = lds + pb;
        const unsigned char* Q = lds + (pb ^ 64u);
        f32x4 acc0 = {}, acc1 = {};
        K_FULL(P, Q, 0,    acc0);
        K_FULL(P, Q, 8192, acc1);
        LOAD_WF(3 * 32768);
        WRITE_ROW(R_S2, nl,      acc0);
        WRITE_ROW(R_S2, 16 + nl, acc1);
    }
    __syncthreads();   // s2 done; s1 dead

    // ---- stage 3: 32 -> 16 rows ----
    {
        unsigned pb = swz(R_S2 + ((unsigned)(2 * nl) << 8) + (unsigned)(kl << 4));
        const unsigned char* P = lds + pb;
        const unsigned char* Q = lds + (pb ^ 64u);
        f32x4 acc0 = {};
        K_FULL(P, Q, 0, acc0);
        LOAD_WF(4 * 32768);
        WRITE_ROW(R_S3, nl, acc0);
    }
    __syncthreads();   // s3 done; s2 dead

    // ---- stage 4: 16 -> 8 rows (lanes nl>=8 clamped) ----
    {
        int dc = (nl < 8) ? nl : 7;
        unsigned pb = swz(R_S3 + ((unsigned)(2 * dc) << 8) + (unsigned)(kl << 4));
        const unsigned char* P = lds + pb;
        const unsigned char* Q = lds + (pb ^ 64u);
        f32x4 acc0 = {};
        K_FULL(P, Q, 0, acc0);
        // prefetch w_stop (4 frags) across the barrier
        #pragma unroll
        for (int kt = 0; kt < 4; ++kt)
            wf[kt] = *(const s16x8*)(wdb + 163840 + ct * 2048 + kt * 512 + lane * 8);
        if (nl < 8) WRITE_ROW(R_S4, nl, acc0);
    }
    __syncthreads();   // s4 done

    // ---- w_stop: 8 rows, K=128, no activation -> global f32 ----
    {
        int dc = (nl < 8) ? nl : 7;
        unsigned pb = swz(R_S4 + ((unsigned)dc << 8) + (unsigned)(kl << 4));
        const unsigned char* P = lds + pb;
        const unsigned char* Q = lds + (pb ^ 64u);
        f32x4 acc = {0.f, 0.f, 0.f, 0.f};
        K_HALF4(wf[0], wf[1], wf[2], wf[3], P, Q, 0, acc);
        int w = w0 + nl;
        if (nl < 8 && w < NWIN) {
            // lane holds channels ct*16+kl*4 .. +3 of window w: one dwordx4
            *(f32x4*)(out + ((size_t)bh * NBLK + (w + 1)) * DQ + ct * 16 + kl * 4) = acc;
        }
    }
#undef K_HALF4
#undef K_FULL
#undef WRITE_ROW
#undef LOAD_WF
#undef LOAD_KIN
}

extern "C" void kernel_launch(void* const* d_in, const int* in_sizes, int n_in,
                              void* d_out, int out_size, void* d_ws, size_t ws_size,
                              hipStream_t stream) {
    const float* kin   = (const float*)d_in[0];
    const float* pe    = (const float*)d_in[1];
    const float* wdown = (const float*)d_in[2];
    const float* wstop = (const float*)d_in[3];
    float* out = (float*)d_out;
    short* wbf  = (short*)d_ws;                       // 180224 shorts (frag-order)
    float* bias = (float*)((char*)d_ws + 360448);     // f32[2048]

    prep_kernel<<<728, 256, 0, stream>>>(wdown, wstop, pe, wbf, bias, out);
    fused_kernel<<<BQ * HQ * NWG_PER_HEAD, 512, 0, stream>>>(kin, wbf, bias, out);
}